// Round 6
// baseline (21316.527 us; speedup 1.0000x reference)
//
#include <hip/hip_runtime.h>

#define TT    1024   // timesteps
#define BATCH 2048
#define NI    6      // input dim
#define NH    38     // hidden
#define NHP   40     // padded hidden row (10 x float4; pads stay 0)
#define NCLS  8      // classes
#define NB    8      // batches per block
#define BLK   512    // 8 waves: 0-2 L1 (152/192 active), 3-7 L2 (304) + 16 prefetch
#define GRID  (BATCH / NB)   // 256 blocks = 1 block/CU, single round

__device__ __forceinline__ float fsig(float v) {
    return __fdividef(1.0f, 1.0f + __expf(-v));
}

// L1: gates live in aligned lane quads -> quad-permute broadcasts
#define QB0 0x8000
#define QB1 0x8055
#define QB2 0x80AA
#define QB3 0x80FF
// L2: octet layout lane = (u<<3)|(g<<1)|half  (BitMode: j = ((i&and)|or)^xor)
#define XOR1   0x041F   // j = i^1 : half-reduce within lane pair
#define OCT_G0 0x0019   // j = (i & 0b11001) | (0<<1) : gate-0 broadcast, same half
#define OCT_G1 0x0059
#define OCT_G2 0x0099
#define OCT_G3 0x00D9
#define SWZ(v, pat) __int_as_float(__builtin_amdgcn_ds_swizzle(__float_as_int(v), pat))

// REGISTER REGIME (rounds 1-5): BLK=1024 forces <=128 regs -> allocator chose
// 64 -> scratch spill -> 51 GB HBM. BLK=512 + __launch_bounds__(512,2) is the
// only validated on-chip config (VGPR~104, WRITE_SIZE 64 KB). Do not change.
__global__ __launch_bounds__(BLK, 2) void lstm2_kernel(
    const float* __restrict__ x,
    const float* __restrict__ Wih0, const float* __restrict__ Whh0, const float* __restrict__ b0,
    const float* __restrict__ Wih1, const float* __restrict__ Whh1, const float* __restrict__ b1,
    const float* __restrict__ Wc,   const float* __restrict__ bc,
    float* __restrict__ out)
{
    __shared__ __align__(16) float h1buf[2][NB][NHP];
    __shared__ __align__(16) float h2buf[2][NB][NHP];
    __shared__ __align__(16) float xbuf[4][NB][8];   // 4-slot x staging, t+2 ahead

    const int tid   = threadIdx.x;
    const int bbase = blockIdx.x * NB;

    // zero h state (both slots; pads stay 0 forever) and xbuf (incl. pads)
    for (int idx = tid; idx < 2 * NB * NHP; idx += BLK) {
        (&h1buf[0][0][0])[idx] = 0.0f;
        (&h2buf[0][0][0])[idx] = 0.0f;
    }
    for (int idx = tid; idx < 4 * NB * 8; idx += BLK) (&xbuf[0][0][0])[idx] = 0.0f;
    __syncthreads();
    // preload x(0), x(1)
    if (tid < 2 * NB * NI) {
        const int slot = tid / (NB * NI), r2 = tid % (NB * NI);
        const int b = r2 / NI, i = r2 % NI;
        xbuf[slot][b][i] = x[((size_t)(bbase + b) * TT + slot) * NI + i];
    }

    // ---- per-thread role setup ----
    int u = 0, g = 0, half = 0;
    bool act = false;
    float w[NHP];                 // L1: Whh0 row; L2 half0: Wih1 row; half1: Whh1 row
    float wx[8] = {0,0,0,0,0,0,0,0};  // L1 only: Wih0 row (padded)
    float bias = 0.0f;
    float cst[NB] = {0,0,0,0,0,0,0,0};

    if (tid < 192) {              // L1: quad layout (u = l>>2, g = l&3)
        const int l = tid;
        u = l >> 2; g = l & 3;
        act = (u < NH);
        const int uc   = act ? u : 0;
        const int grow = g * NH + uc;
        const float* rw = Whh0 + (size_t)grow * NH;
        #pragma unroll
        for (int k = 0; k < NH; ++k) w[k] = rw[k];
        w[38] = 0.f; w[39] = 0.f;
        const float* rx = Wih0 + (size_t)grow * NI;
        #pragma unroll
        for (int i = 0; i < NI; ++i) wx[i] = rx[i];
        bias = b0[grow];
    } else if (tid < 496) {       // L2: octet layout (u = l>>3, g = (l>>1)&3, half = l&1)
        const int l = tid - 192;
        u = l >> 3; g = (l >> 1) & 3; half = l & 1;
        act = true;
        const int grow = g * NH + u;
        const float* rw = (half ? Whh1 : Wih1) + (size_t)grow * NH;
        #pragma unroll
        for (int k = 0; k < NH; ++k) w[k] = rw[k];
        w[38] = 0.f; w[39] = 0.f;
        bias = b1[grow];
    }

    // own-gate activation: gate 2 is tanh(a) = 2*sigmoid(2a) - 1
    const float k1 = (g == 2) ? 2.0f : 1.0f;
    const float k2 = (g == 2) ? 2.0f : 1.0f;
    const float k3 = (g == 2) ? -1.0f : 0.0f;

    __syncthreads();

    // Layer-pipelined recurrence: iteration k computes h1(k) AND h2(k-1).
    // h2(k-1) needs h1(k-1), h2(k-2) -- both from iteration k-1 => ONE barrier/iter.
    #pragma unroll 1
    for (int k = 0; k <= TT; ++k) {
        const int cur = k & 1, prv = cur ^ 1, xs = k & 3;

        if (tid < 192) {
            if (k < TT) {
                // layer 1: a = b0 + Wih0 x(k) + Whh0 h1(k-1)
                float acc[NB];
                #pragma unroll
                for (int b = 0; b < NB; ++b) {
                    const float4 x0 = *(const float4*)(&xbuf[xs][b][0]);
                    const float4 x1 = *(const float4*)(&xbuf[xs][b][4]);
                    float a = bias;
                    a += wx[0]*x0.x; a += wx[1]*x0.y; a += wx[2]*x0.z; a += wx[3]*x0.w;
                    a += wx[4]*x1.x; a += wx[5]*x1.y;
                    acc[b] = a;
                }
                const float4* h4 = (const float4*)(&h1buf[prv][0][0]);
                #pragma unroll
                for (int c4 = 0; c4 < 10; ++c4) {
                    #pragma unroll
                    for (int b = 0; b < NB; ++b) {       // 8 independent chains
                        const float4 hv = h4[b * 10 + c4];   // wave-broadcast
                        acc[b] += w[4*c4+0] * hv.x; acc[b] += w[4*c4+1] * hv.y;
                        acc[b] += w[4*c4+2] * hv.z; acc[b] += w[4*c4+3] * hv.w;
                    }
                }
                #pragma unroll
                for (int b = 0; b < NB; ++b) {
                    const float v  = fsig(acc[b] * k1) * k2 + k3;
                    const float gi = SWZ(v, QB0);
                    const float gf = SWZ(v, QB1);
                    const float gg = SWZ(v, QB2);
                    const float go = SWZ(v, QB3);
                    const float c  = gf * cst[b] + gi * gg;
                    cst[b] = c;
                    const float h = go * (2.0f * fsig(2.0f * c) - 1.0f);
                    if (act && g == 0) h1buf[cur][b][u] = h;
                }
            }
        } else if (tid < 496) {
            if (k >= 1) {
                // layer 2 at time k-1: a = b1 + Wih1 h1(k-1) + Whh1 h2(k-2)
                // row split across lane pair: half0 does Wih1 part, half1 Whh1 part
                float acc[NB];
                #pragma unroll
                for (int b = 0; b < NB; ++b) acc[b] = 0.0f;
                const float4* h4 = half ? (const float4*)(&h2buf[prv][0][0])
                                        : (const float4*)(&h1buf[prv][0][0]);
                #pragma unroll
                for (int c4 = 0; c4 < 10; ++c4) {
                    #pragma unroll
                    for (int b = 0; b < NB; ++b) {
                        const float4 hv = h4[b * 10 + c4];   // 2 addrs/wave: free
                        acc[b] += w[4*c4+0] * hv.x; acc[b] += w[4*c4+1] * hv.y;
                        acc[b] += w[4*c4+2] * hv.z; acc[b] += w[4*c4+3] * hv.w;
                    }
                }
                #pragma unroll
                for (int b = 0; b < NB; ++b) {
                    const float a  = acc[b] + SWZ(acc[b], XOR1) + bias;
                    const float v  = fsig(a * k1) * k2 + k3;
                    const float gi = SWZ(v, OCT_G0);
                    const float gf = SWZ(v, OCT_G1);
                    const float gg = SWZ(v, OCT_G2);
                    const float go = SWZ(v, OCT_G3);
                    const float c  = gf * cst[b] + gi * gg;
                    cst[b] = c;
                    const float h = go * (2.0f * fsig(2.0f * c) - 1.0f);
                    if (g == 0 && half == 0) h2buf[cur][b][u] = h;
                }
            }
        } else {
            // x prefetch, 2 iterations ahead
            if (k + 2 < TT) {
                const int p = tid - 496;
                #pragma unroll
                for (int e = p; e < NB * NI; e += 16) {
                    const int b = e / NI, i = e % NI;
                    xbuf[(k + 2) & 3][b][i] =
                        x[((size_t)(bbase + b) * TT + (k + 2)) * NI + i];
                }
            }
        }
        __syncthreads();
    }

    // epilogue: out = h2(TT-1) @ Wc.T + bc ; written at k=TT into slot TT&1 = 0
    if (tid < NB * NCLS) {
        const int b = tid >> 3, c = tid & 7;
        float acc = bc[c];
        #pragma unroll
        for (int k = 0; k < NH; ++k) acc += Wc[c * NH + k] * h2buf[0][b][k];
        out[(size_t)(bbase + b) * NCLS + c] = acc;
    }
}

extern "C" void kernel_launch(void* const* d_in, const int* in_sizes, int n_in,
                              void* d_out, int out_size, void* d_ws, size_t ws_size,
                              hipStream_t stream) {
    const float* x    = (const float*)d_in[0];
    const float* Wih0 = (const float*)d_in[1];
    const float* Whh0 = (const float*)d_in[2];
    const float* b0   = (const float*)d_in[3];
    const float* Wih1 = (const float*)d_in[4];
    const float* Whh1 = (const float*)d_in[5];
    const float* b1   = (const float*)d_in[6];
    const float* Wc   = (const float*)d_in[7];
    const float* bc   = (const float*)d_in[8];
    float* out = (float*)d_out;

    hipLaunchKernelGGL(lstm2_kernel, dim3(GRID), dim3(BLK), 0, stream,
                       x, Wih0, Whh0, b0, Wih1, Whh1, b1, Wc, bc, out);
}